// Round 1
// baseline (4673.074 us; speedup 1.0000x reference)
//
#include <hip/hip_runtime.h>
#include <math.h>

#define TPB 256

// ---- analytic Wigner-3j constants (derived as Gaunt coefficients in the
// reference's real-SH basis; see session notes). ----
#define R10   0.31622776601683794f  // 1/sqrt(10)
#define R30   0.18257418583505536f  // 1/sqrt(30)
#define R30x2 0.36514837167011072f  // 2/sqrt(30)
// C(2,2,2): 7-way |max| tie in the reference's sign fix -> coin flip.
// C222_SIGN=+1 bakes the (6/7-likely) flipped-Gaunt orientation (C[0][0][2]=+2/sqrt70).
// If d-path lo=2 output has wrong sign (absmax ~O(10)), set to -1.0f.
#define C222_SIGN (1.0f)
#define CCA (C222_SIGN * 0.23904572186687872f) // 2/sqrt(70)
#define CCB (C222_SIGN * 0.20701966780270623f) // sqrt(3/70)
#define CCC (C222_SIGN * 0.11952286093343936f) // 1/sqrt(70)

__device__ __forceinline__ void atomAddF(float* p, float v) {
    __hip_atomic_fetch_add(p, v, __ATOMIC_RELAXED, __HIP_MEMORY_SCOPE_AGENT);
}

template<int M>
__device__ __forceinline__ void fc_eval(const float* sW1T, const float* sW2,
                                        const float emb[12], float* acc)
{
#pragma unroll
    for (int m = 0; m < M; ++m) acc[m] = 0.f;
#pragma unroll 2
    for (int j = 0; j < 64; ++j) {
        const float4* w1r = (const float4*)(sW1T + j * 12);
        float4 A = w1r[0], B = w1r[1], C = w1r[2];
        float t = A.x*emb[0] + A.y*emb[1] + A.z*emb[2] + A.w*emb[3]
                + B.x*emb[4] + B.y*emb[5] + B.z*emb[6] + B.w*emb[7]
                + C.x*emb[8] + C.y*emb[9];
        t = fmaxf(t, 0.f);
        const float4* w2r = (const float4*)(sW2 + j * M);
#pragma unroll
        for (int q = 0; q < M / 4; ++q) {
            float4 V = w2r[q];
            acc[4*q+0] = fmaf(t, V.x, acc[4*q+0]);
            acc[4*q+1] = fmaf(t, V.y, acc[4*q+1]);
            acc[4*q+2] = fmaf(t, V.z, acc[4*q+2]);
            acc[4*q+3] = fmaf(t, V.w, acc[4*q+3]);
        }
    }
}

__global__ __launch_bounds__(TPB) void eqconv_edge_kernel(
    const float* __restrict__ f_in,
    const int*   __restrict__ eidx,
    const float* __restrict__ pos,
    const float* __restrict__ W1s_g, const float* __restrict__ W2s_g,
    const float* __restrict__ W1p_g, const float* __restrict__ W2p_g,
    const float* __restrict__ W1d_g, const float* __restrict__ W2d_g,
    float* __restrict__ out,
    int E, float snorm)
{
    __shared__ __align__(16) float smem[11264];
    float* tW1s = smem;            // 64x12 (W1_s^T, padded 10->12)
    float* tW1p = smem + 768;
    float* tW1d = smem + 1536;
    float* sW2s = smem + 2304;     // 64x12
    float* sW2p = smem + 3072;     // 64x48
    float* sW2d = smem + 6144;     // 64x80

    const int tid = threadIdx.x;
    // sqrt(2)/(8*sqrt(10)) [FC scales] * snorm [1/sqrt(num_neighbors)]
    const float base = 0.05590169943749474f * snorm;

    for (int idx = tid; idx < 768; idx += TPB) {
        int j = idx / 12, i = idx - j * 12;
        tW1s[idx] = (i < 10) ? W1s_g[i * 64 + j] : 0.f;
        tW1p[idx] = (i < 10) ? W1p_g[i * 64 + j] : 0.f;
        tW1d[idx] = (i < 10) ? W1d_g[i * 64 + j] : 0.f;
    }
    for (int idx = tid; idx < 768; idx += TPB)
        sW2s[idx] = W2s_g[idx] * base;                   // all S ins consts == 1
    for (int idx = tid; idx < 3072; idx += TPB) {
        int m = idx % 48;
        float k = (m < 12) ? 0.40824829046386307f        // ins(l2=0,lo=1): pw/sqrt3
                : (m < 24) ? 0.33333333333333333f        // ins(1,0): 1/3
                : (m < 36) ? 1.29099444873580560f        // ins(1,2): sqrt(5/3)
                           : 0.70710678118654752f;       // ins(2,1): 1/sqrt2
        sW2p[idx] = W2p_g[idx] * (base * k);
    }
    for (int idx = tid; idx < 5120; idx += TPB) {
        int m = idx % 80;
        float k = (m < 20) ? 0.31622776601683794f        // ins(0,2): 1/sqrt10
                : (m < 40) ? 0.77459666924148340f        // ins(1,1): sqrt(3/5)
                : (m < 60) ? 0.2f                        // ins(2,0): 1/5
                           : 0.70710678118654752f;       // ins(2,2): 1/sqrt2
        sW2d[idx] = W2d_g[idx] * (base * k);
    }
    __syncthreads();

    int e = blockIdx.x * TPB + tid;
    if (e >= E) return;

    const int row = eidx[e];
    const int col = eidx[E + e];

    float ex = pos[row * 3 + 0] - pos[col * 3 + 0];
    float ey = pos[row * 3 + 1] - pos[col * 3 + 1];
    float ez = pos[row * 3 + 2] - pos[col * 3 + 2];
    float r2 = ex * ex + ey * ey + ez * ez + 1e-12f;
    float r = sqrtf(r2);
    float rinv = 1.0f / r;
    float x = ex * rinv, y = ey * rinv, z = ez * rinv;

    // spherical harmonics in the reference's basis/order
    float sh1 = 1.7320508075688772f * x;
    float sh2 = 1.7320508075688772f * y;
    float sh3 = 1.7320508075688772f * z;
    float sh4 = 3.8729833462074170f * x * z;
    float sh5 = 3.8729833462074170f * x * y;
    float sh6 = 1.1180339887498949f * (2.f * y * y - x * x - z * z);
    float sh7 = 3.8729833462074170f * y * z;
    float sh8 = 1.9364916731037085f * (z * z - x * x);

    // radial embedding: sus(d+1)*sus(1-d) == exp(-2/(1-d^2)) for |d|<1
    float emb[12];
    {
        const float F = (float)(1.14136 * 7.38905609893065 * 3.1622776601683795);
        const float inv_step = 2.2f;  // 11/5
#pragma unroll
        for (int i = 0; i < 10; ++i) {
            float v = (float)(i + 1) * (5.0f / 11.0f);
            float d = (r - v) * inv_step;
            float d2 = d * d;
            emb[i] = (d2 < 1.0f) ? F * expf(-2.0f / (1.0f - d2)) : 0.f;
        }
        emb[10] = 0.f; emb[11] = 0.f;
    }

    const float* fr = f_in + (size_t)row * 162;
    float* o = out + (size_t)col * 108;

    // ---------------- S path (x_s: 1x1) ----------------
    {
        float ws[12];
        fc_eval<12>(tW1s, sW2s, emb, ws);
        float2 v0 = *(const float2*)(fr);
        float X = v0.x + v0.y;
#pragma unroll
        for (int w = 0; w < 4; ++w) {
            atomAddF(o + w, X * ws[w]);
            float t1 = X * ws[4 + w];
            atomAddF(o + 4 + w * 3 + 0, t1 * sh1);
            atomAddF(o + 4 + w * 3 + 1, t1 * sh2);
            atomAddF(o + 4 + w * 3 + 2, t1 * sh3);
            float t2 = X * ws[8 + w];
            atomAddF(o + 16 + w * 5 + 0, t2 * sh4);
            atomAddF(o + 16 + w * 5 + 1, t2 * sh5);
            atomAddF(o + 16 + w * 5 + 2, t2 * sh6);
            atomAddF(o + 16 + w * 5 + 3, t2 * sh7);
            atomAddF(o + 16 + w * 5 + 4, t2 * sh8);
        }
    }

    // ---------------- P path (x_p: 3x3) ----------------
    {
        float wp[48];
        fc_eval<48>(tW1p, sW2p, emb, wp);
        float op0[4] = {0.f, 0.f, 0.f, 0.f};
        float op1[12], op2[20];
#pragma unroll
        for (int t = 0; t < 12; ++t) op1[t] = 0.f;
#pragma unroll
        for (int t = 0; t < 20; ++t) op2[t] = 0.f;
#pragma unroll
        for (int u = 0; u < 3; ++u) {
            float2 a0 = *(const float2*)(fr + ((1 + u) * 9 + 1) * 2);
            float2 a1 = *(const float2*)(fr + ((1 + u) * 9 + 2) * 2);
            float2 a2 = *(const float2*)(fr + ((1 + u) * 9 + 3) * 2);
            float x0 = a0.x + a0.y, x1 = a1.x + a1.y, x2 = a2.x + a2.y;
            float dot = x0 * sh1 + x1 * sh2 + x2 * sh3;                  // ins(1,0)
            // ins(1,2): C(1,1,2)
            float ya0 = R10 * (x0 * sh3 + x2 * sh1);
            float ya1 = R10 * (x0 * sh2 + x1 * sh1);
            float ya2 = R30 * (2.f * x1 * sh2 - x0 * sh1 - x2 * sh3);
            float ya3 = R10 * (x1 * sh3 + x2 * sh2);
            float ya4 = R10 * (x2 * sh3 - x0 * sh1);
            // ins(2,1): C(1,2,1)
            float yb0 = R10 * (x2 * sh4 + x1 * sh5 - x0 * sh8) - R30 * x0 * sh6;
            float yb1 = R10 * (x0 * sh5 + x2 * sh7) + R30x2 * x1 * sh6;
            float yb2 = R10 * (x0 * sh4 + x1 * sh7 + x2 * sh8) - R30 * x2 * sh6;
#pragma unroll
            for (int w = 0; w < 4; ++w) {
                float wa = wp[u * 4 + w];
                float wb = wp[12 + u * 4 + w];
                float wc = wp[24 + u * 4 + w];
                float wd2 = wp[36 + u * 4 + w];
                op0[w] = fmaf(dot, wb, op0[w]);
                op1[w * 3 + 0] = fmaf(x0, wa, fmaf(yb0, wd2, op1[w * 3 + 0]));
                op1[w * 3 + 1] = fmaf(x1, wa, fmaf(yb1, wd2, op1[w * 3 + 1]));
                op1[w * 3 + 2] = fmaf(x2, wa, fmaf(yb2, wd2, op1[w * 3 + 2]));
                op2[w * 5 + 0] = fmaf(ya0, wc, op2[w * 5 + 0]);
                op2[w * 5 + 1] = fmaf(ya1, wc, op2[w * 5 + 1]);
                op2[w * 5 + 2] = fmaf(ya2, wc, op2[w * 5 + 2]);
                op2[w * 5 + 3] = fmaf(ya3, wc, op2[w * 5 + 3]);
                op2[w * 5 + 4] = fmaf(ya4, wc, op2[w * 5 + 4]);
            }
        }
#pragma unroll
        for (int w = 0; w < 4; ++w) atomAddF(o + 36 + w, op0[w]);
#pragma unroll
        for (int t = 0; t < 12; ++t) atomAddF(o + 40 + t, op1[t]);
#pragma unroll
        for (int t = 0; t < 20; ++t) atomAddF(o + 52 + t, op2[t]);
    }

    // ---------------- D path (x_d: 5x5) ----------------
    {
        float wd[80];
        fc_eval<80>(tW1d, sW2d, emb, wd);
        float od0[4] = {0.f, 0.f, 0.f, 0.f};
        float od1[12], od2[20];
#pragma unroll
        for (int t = 0; t < 12; ++t) od1[t] = 0.f;
#pragma unroll
        for (int t = 0; t < 20; ++t) od2[t] = 0.f;
#pragma unroll
        for (int u = 0; u < 5; ++u) {
            float2 b0 = *(const float2*)(fr + ((4 + u) * 9 + 4) * 2);
            float2 b1 = *(const float2*)(fr + ((4 + u) * 9 + 5) * 2);
            float2 b2 = *(const float2*)(fr + ((4 + u) * 9 + 6) * 2);
            float2 b3 = *(const float2*)(fr + ((4 + u) * 9 + 7) * 2);
            float2 b4 = *(const float2*)(fr + ((4 + u) * 9 + 8) * 2);
            float x0 = b0.x + b0.y, x1 = b1.x + b1.y, x2 = b2.x + b2.y;
            float x3 = b3.x + b3.y, x4 = b4.x + b4.y;
            float dot = x0 * sh4 + x1 * sh5 + x2 * sh6 + x3 * sh7 + x4 * sh8;  // ins(2,0)
            // ins(1,1): C(2,1,1)
            float yb0 = R10 * (x0 * sh3 + x1 * sh2 - x4 * sh1) - R30 * x2 * sh1;
            float yb1 = R10 * (x1 * sh1 + x3 * sh3) + R30x2 * x2 * sh2;
            float yb2 = R10 * (x0 * sh1 + x3 * sh2 + x4 * sh3) - R30 * x2 * sh3;
            // ins(2,2): C(2,2,2) in the C222_SIGN orientation
            float yc0 = CCA * (x2 * sh4 + x0 * sh6) - CCB * (x1 * sh7 + x3 * sh5);
            float yc1 = CCB * (x1 * sh8 + x4 * sh5 - x0 * sh7 - x3 * sh4)
                      - CCC * (x1 * sh6 + x2 * sh5);
            float yc2 = CCA * (x0 * sh4 - x2 * sh6 + x4 * sh8)
                      - CCC * (x1 * sh5 + x3 * sh7);
            float yc3 = -CCB * (x0 * sh5 + x1 * sh4 + x3 * sh8 + x4 * sh7)
                      - CCC * (x2 * sh7 + x3 * sh6);
            float yc4 = CCB * (x1 * sh5 - x3 * sh7) + CCA * (x2 * sh8 + x4 * sh6);
#pragma unroll
            for (int w = 0; w < 4; ++w) {
                float wa = wd[u * 4 + w];
                float wb = wd[20 + u * 4 + w];
                float wc = wd[40 + u * 4 + w];
                float we = wd[60 + u * 4 + w];
                od0[w] = fmaf(dot, wc, od0[w]);
                od1[w * 3 + 0] = fmaf(yb0, wb, od1[w * 3 + 0]);
                od1[w * 3 + 1] = fmaf(yb1, wb, od1[w * 3 + 1]);
                od1[w * 3 + 2] = fmaf(yb2, wb, od1[w * 3 + 2]);
                od2[w * 5 + 0] = fmaf(x0, wa, fmaf(yc0, we, od2[w * 5 + 0]));
                od2[w * 5 + 1] = fmaf(x1, wa, fmaf(yc1, we, od2[w * 5 + 1]));
                od2[w * 5 + 2] = fmaf(x2, wa, fmaf(yc2, we, od2[w * 5 + 2]));
                od2[w * 5 + 3] = fmaf(x3, wa, fmaf(yc3, we, od2[w * 5 + 3]));
                od2[w * 5 + 4] = fmaf(x4, wa, fmaf(yc4, we, od2[w * 5 + 4]));
            }
        }
#pragma unroll
        for (int w = 0; w < 4; ++w) atomAddF(o + 72 + w, od0[w]);
#pragma unroll
        for (int t = 0; t < 12; ++t) atomAddF(o + 76 + t, od1[t]);
#pragma unroll
        for (int t = 0; t < 20; ++t) atomAddF(o + 88 + t, od2[t]);
    }
}

extern "C" void kernel_launch(void* const* d_in, const int* in_sizes, int n_in,
                              void* d_out, int out_size, void* d_ws, size_t ws_size,
                              hipStream_t stream) {
    const float* f_in = (const float*)d_in[0];
    const int*   eidx = (const int*)d_in[1];
    const float* pos  = (const float*)d_in[2];
    // d_in[3] = max_radius (5), d_in[4] = num_nodes — constants folded on host
    const float* W1s = (const float*)d_in[5];
    const float* W2s = (const float*)d_in[6];
    const float* W1p = (const float*)d_in[7];
    const float* W2p = (const float*)d_in[8];
    const float* W1d = (const float*)d_in[9];
    const float* W2d = (const float*)d_in[10];

    const int E = in_sizes[1] / 2;
    const int N = in_sizes[0] / 162;
    const float snorm = (float)(1.0 / sqrt((double)E / (double)N));

    hipMemsetAsync(d_out, 0, (size_t)out_size * sizeof(float), stream);

    const int blocks = (E + TPB - 1) / TPB;
    eqconv_edge_kernel<<<blocks, TPB, 0, stream>>>(
        f_in, eidx, pos, W1s, W2s, W1p, W2p, W1d, W2d,
        (float*)d_out, E, snorm);
}

// Round 2
// 4667.359 us; speedup vs baseline: 1.0012x; 1.0012x over previous
//
#include <hip/hip_runtime.h>
#include <math.h>

#define TPB 256

// ---- analytic Wigner-3j constants (Gaunt coefficients in the reference's
// real-SH basis; verified R1: absmax 0.0156). ----
#define R10   0.31622776601683794f  // 1/sqrt(10)
#define R30   0.18257418583505536f  // 1/sqrt(30)
#define R30x2 0.36514837167011072f  // 2/sqrt(30)
#define C222_SIGN (1.0f)            // verified R1
#define CCA (C222_SIGN * 0.23904572186687872f) // 2/sqrt(70)
#define CCB (C222_SIGN * 0.20701966780270623f) // sqrt(3/70)
#define CCC (C222_SIGN * 0.11952286093343936f) // 1/sqrt(70)

__device__ __forceinline__ void atomAddF(float* p, float v) {
    __hip_atomic_fetch_add(p, v, __ATOMIC_RELAXED, __HIP_MEMORY_SCOPE_AGENT);
}

template<int M>
__device__ __forceinline__ void fc_eval(const float* sW1T, const float* sW2,
                                        const float emb[12], float* acc)
{
#pragma unroll
    for (int m = 0; m < M; ++m) acc[m] = 0.f;
#pragma unroll 2
    for (int j = 0; j < 64; ++j) {
        const float4* w1r = (const float4*)(sW1T + j * 12);
        float4 A = w1r[0], B = w1r[1], C = w1r[2];
        float t = A.x*emb[0] + A.y*emb[1] + A.z*emb[2] + A.w*emb[3]
                + B.x*emb[4] + B.y*emb[5] + B.z*emb[6] + B.w*emb[7]
                + C.x*emb[8] + C.y*emb[9];
        t = fmaxf(t, 0.f);
        const float4* w2r = (const float4*)(sW2 + j * M);
#pragma unroll
        for (int q = 0; q < M / 4; ++q) {
            float4 V = w2r[q];
            acc[4*q+0] = fmaf(t, V.x, acc[4*q+0]);
            acc[4*q+1] = fmaf(t, V.y, acc[4*q+1]);
            acc[4*q+2] = fmaf(t, V.z, acc[4*q+2]);
            acc[4*q+3] = fmaf(t, V.w, acc[4*q+3]);
        }
    }
}

// ============ phase 1: histogram of col ============
__global__ __launch_bounds__(256) void count_kernel(const int* __restrict__ col,
                                                    int* __restrict__ cnt, int E) {
    int e = blockIdx.x * 256 + threadIdx.x;
    if (e < E) atomicAdd(&cnt[col[e]], 1);
}

// ============ phase 2: exclusive scan (1 block, 4 elems/thread) ============
__global__ __launch_bounds__(1024) void scan_kernel(const int* __restrict__ cnt,
                                                    int* __restrict__ offs,
                                                    int* __restrict__ cursor, int N) {
    __shared__ int sdata[1024];
    __shared__ int stotal;
    const int tid = threadIdx.x;
    if (tid == 0) stotal = 0;
    __syncthreads();
    for (int base = 0; base < N; base += 4096) {
        int i0 = base + tid * 4;
        int v0 = (i0 + 0 < N) ? cnt[i0 + 0] : 0;
        int v1 = (i0 + 1 < N) ? cnt[i0 + 1] : 0;
        int v2 = (i0 + 2 < N) ? cnt[i0 + 2] : 0;
        int v3 = (i0 + 3 < N) ? cnt[i0 + 3] : 0;
        int s = v0 + v1 + v2 + v3;
        sdata[tid] = s;
        __syncthreads();
        for (int d = 1; d < 1024; d <<= 1) {
            int t = (tid >= d) ? sdata[tid - d] : 0;
            __syncthreads();
            sdata[tid] += t;
            __syncthreads();
        }
        int excl = sdata[tid] - s + stotal;
        if (i0 + 0 < N) { offs[i0 + 0] = excl; cursor[i0 + 0] = excl; }
        excl += v0;
        if (i0 + 1 < N) { offs[i0 + 1] = excl; cursor[i0 + 1] = excl; }
        excl += v1;
        if (i0 + 2 < N) { offs[i0 + 2] = excl; cursor[i0 + 2] = excl; }
        excl += v2;
        if (i0 + 3 < N) { offs[i0 + 3] = excl; cursor[i0 + 3] = excl; }
        __syncthreads();
        if (tid == 1023) stotal += sdata[1023];
        __syncthreads();
    }
    if (tid == 0) offs[N] = stotal;
}

// ============ phase 3: per-edge compute -> sorted summand row ============
__global__ __launch_bounds__(TPB) void eqconv_compute_kernel(
    const float* __restrict__ f_in,
    const int*   __restrict__ eidx,
    const float* __restrict__ pos,
    const float* __restrict__ W1s_g, const float* __restrict__ W2s_g,
    const float* __restrict__ W1p_g, const float* __restrict__ W2p_g,
    const float* __restrict__ W1d_g, const float* __restrict__ W2d_g,
    int* __restrict__ cursor,
    float* __restrict__ summand,
    int E, float snorm)
{
    __shared__ __align__(16) float smem[11264];
    float* tW1s = smem;            // 64x12 (W1^T, padded 10->12)
    float* tW1p = smem + 768;
    float* tW1d = smem + 1536;
    float* sW2s = smem + 2304;     // 64x12
    float* sW2p = smem + 3072;     // 64x48
    float* sW2d = smem + 6144;     // 64x80

    const int tid = threadIdx.x;
    const float base = 0.05590169943749474f * snorm; // sqrt2/(8*sqrt10) * snorm

    for (int idx = tid; idx < 768; idx += TPB) {
        int j = idx / 12, i = idx - j * 12;
        tW1s[idx] = (i < 10) ? W1s_g[i * 64 + j] : 0.f;
        tW1p[idx] = (i < 10) ? W1p_g[i * 64 + j] : 0.f;
        tW1d[idx] = (i < 10) ? W1d_g[i * 64 + j] : 0.f;
    }
    for (int idx = tid; idx < 768; idx += TPB)
        sW2s[idx] = W2s_g[idx] * base;
    for (int idx = tid; idx < 3072; idx += TPB) {
        int m = idx % 48;
        float k = (m < 12) ? 0.40824829046386307f
                : (m < 24) ? 0.33333333333333333f
                : (m < 36) ? 1.29099444873580560f
                           : 0.70710678118654752f;
        sW2p[idx] = W2p_g[idx] * (base * k);
    }
    for (int idx = tid; idx < 5120; idx += TPB) {
        int m = idx % 80;
        float k = (m < 20) ? 0.31622776601683794f
                : (m < 40) ? 0.77459666924148340f
                : (m < 60) ? 0.2f
                           : 0.70710678118654752f;
        sW2d[idx] = W2d_g[idx] * (base * k);
    }
    __syncthreads();

    int e = blockIdx.x * TPB + tid;
    if (e >= E) return;

    const int row = eidx[e];
    const int col = eidx[E + e];
    // claim the sorted slot early; latency hides under the FC compute
    const int p = atomicAdd(&cursor[col], 1);

    float ex = pos[row * 3 + 0] - pos[col * 3 + 0];
    float ey = pos[row * 3 + 1] - pos[col * 3 + 1];
    float ez = pos[row * 3 + 2] - pos[col * 3 + 2];
    float r2 = ex * ex + ey * ey + ez * ez + 1e-12f;
    float r = sqrtf(r2);
    float rinv = 1.0f / r;
    float x = ex * rinv, y = ey * rinv, z = ez * rinv;

    float sh1 = 1.7320508075688772f * x;
    float sh2 = 1.7320508075688772f * y;
    float sh3 = 1.7320508075688772f * z;
    float sh4 = 3.8729833462074170f * x * z;
    float sh5 = 3.8729833462074170f * x * y;
    float sh6 = 1.1180339887498949f * (2.f * y * y - x * x - z * z);
    float sh7 = 3.8729833462074170f * y * z;
    float sh8 = 1.9364916731037085f * (z * z - x * x);

    float emb[12];
    {
        const float F = (float)(1.14136 * 7.38905609893065 * 3.1622776601683795);
        const float inv_step = 2.2f;
#pragma unroll
        for (int i = 0; i < 10; ++i) {
            float v = (float)(i + 1) * (5.0f / 11.0f);
            float d = (r - v) * inv_step;
            float d2 = d * d;
            emb[i] = (d2 < 1.0f) ? F * expf(-2.0f / (1.0f - d2)) : 0.f;
        }
        emb[10] = 0.f; emb[11] = 0.f;
    }

    const float* fr = f_in + (size_t)row * 162;
    float4* rowv = (float4*)(summand + (size_t)p * 108);

    // ---------------- S path ----------------
    {
        float ws[12];
        fc_eval<12>(tW1s, sW2s, emb, ws);
        float2 v0 = *(const float2*)(fr);
        float X = v0.x + v0.y;
        float b[36] __attribute__((aligned(16)));
#pragma unroll
        for (int w = 0; w < 4; ++w) {
            b[w] = X * ws[w];
            float t1 = X * ws[4 + w];
            b[4 + w * 3 + 0] = t1 * sh1;
            b[4 + w * 3 + 1] = t1 * sh2;
            b[4 + w * 3 + 2] = t1 * sh3;
            float t2 = X * ws[8 + w];
            b[16 + w * 5 + 0] = t2 * sh4;
            b[16 + w * 5 + 1] = t2 * sh5;
            b[16 + w * 5 + 2] = t2 * sh6;
            b[16 + w * 5 + 3] = t2 * sh7;
            b[16 + w * 5 + 4] = t2 * sh8;
        }
#pragma unroll
        for (int q = 0; q < 9; ++q) rowv[q] = ((const float4*)b)[q];
    }

    // ---------------- P path ----------------
    {
        float wp[48];
        fc_eval<48>(tW1p, sW2p, emb, wp);
        float b[36] __attribute__((aligned(16)));
        float* op0 = b;       // 4
        float* op1 = b + 4;   // 12
        float* op2 = b + 16;  // 20
#pragma unroll
        for (int t = 0; t < 36; ++t) b[t] = 0.f;
#pragma unroll
        for (int u = 0; u < 3; ++u) {
            float2 a0 = *(const float2*)(fr + ((1 + u) * 9 + 1) * 2);
            float2 a1 = *(const float2*)(fr + ((1 + u) * 9 + 2) * 2);
            float2 a2 = *(const float2*)(fr + ((1 + u) * 9 + 3) * 2);
            float x0 = a0.x + a0.y, x1 = a1.x + a1.y, x2 = a2.x + a2.y;
            float dot = x0 * sh1 + x1 * sh2 + x2 * sh3;
            float ya0 = R10 * (x0 * sh3 + x2 * sh1);
            float ya1 = R10 * (x0 * sh2 + x1 * sh1);
            float ya2 = R30 * (2.f * x1 * sh2 - x0 * sh1 - x2 * sh3);
            float ya3 = R10 * (x1 * sh3 + x2 * sh2);
            float ya4 = R10 * (x2 * sh3 - x0 * sh1);
            float yb0 = R10 * (x2 * sh4 + x1 * sh5 - x0 * sh8) - R30 * x0 * sh6;
            float yb1 = R10 * (x0 * sh5 + x2 * sh7) + R30x2 * x1 * sh6;
            float yb2 = R10 * (x0 * sh4 + x1 * sh7 + x2 * sh8) - R30 * x2 * sh6;
#pragma unroll
            for (int w = 0; w < 4; ++w) {
                float wa = wp[u * 4 + w];
                float wb = wp[12 + u * 4 + w];
                float wc = wp[24 + u * 4 + w];
                float wd2 = wp[36 + u * 4 + w];
                op0[w] = fmaf(dot, wb, op0[w]);
                op1[w * 3 + 0] = fmaf(x0, wa, fmaf(yb0, wd2, op1[w * 3 + 0]));
                op1[w * 3 + 1] = fmaf(x1, wa, fmaf(yb1, wd2, op1[w * 3 + 1]));
                op1[w * 3 + 2] = fmaf(x2, wa, fmaf(yb2, wd2, op1[w * 3 + 2]));
                op2[w * 5 + 0] = fmaf(ya0, wc, op2[w * 5 + 0]);
                op2[w * 5 + 1] = fmaf(ya1, wc, op2[w * 5 + 1]);
                op2[w * 5 + 2] = fmaf(ya2, wc, op2[w * 5 + 2]);
                op2[w * 5 + 3] = fmaf(ya3, wc, op2[w * 5 + 3]);
                op2[w * 5 + 4] = fmaf(ya4, wc, op2[w * 5 + 4]);
            }
        }
#pragma unroll
        for (int q = 0; q < 9; ++q) rowv[9 + q] = ((const float4*)b)[q];
    }

    // ---------------- D path ----------------
    {
        float wd[80];
        fc_eval<80>(tW1d, sW2d, emb, wd);
        float b[36] __attribute__((aligned(16)));
        float* od0 = b;       // 4
        float* od1 = b + 4;   // 12
        float* od2 = b + 16;  // 20
#pragma unroll
        for (int t = 0; t < 36; ++t) b[t] = 0.f;
#pragma unroll
        for (int u = 0; u < 5; ++u) {
            float2 b0 = *(const float2*)(fr + ((4 + u) * 9 + 4) * 2);
            float2 b1 = *(const float2*)(fr + ((4 + u) * 9 + 5) * 2);
            float2 b2 = *(const float2*)(fr + ((4 + u) * 9 + 6) * 2);
            float2 b3 = *(const float2*)(fr + ((4 + u) * 9 + 7) * 2);
            float2 b4 = *(const float2*)(fr + ((4 + u) * 9 + 8) * 2);
            float x0 = b0.x + b0.y, x1 = b1.x + b1.y, x2 = b2.x + b2.y;
            float x3 = b3.x + b3.y, x4 = b4.x + b4.y;
            float dot = x0 * sh4 + x1 * sh5 + x2 * sh6 + x3 * sh7 + x4 * sh8;
            float yb0 = R10 * (x0 * sh3 + x1 * sh2 - x4 * sh1) - R30 * x2 * sh1;
            float yb1 = R10 * (x1 * sh1 + x3 * sh3) + R30x2 * x2 * sh2;
            float yb2 = R10 * (x0 * sh1 + x3 * sh2 + x4 * sh3) - R30 * x2 * sh3;
            float yc0 = CCA * (x2 * sh4 + x0 * sh6) - CCB * (x1 * sh7 + x3 * sh5);
            float yc1 = CCB * (x1 * sh8 + x4 * sh5 - x0 * sh7 - x3 * sh4)
                      - CCC * (x1 * sh6 + x2 * sh5);
            float yc2 = CCA * (x0 * sh4 - x2 * sh6 + x4 * sh8)
                      - CCC * (x1 * sh5 + x3 * sh7);
            float yc3 = -CCB * (x0 * sh5 + x1 * sh4 + x3 * sh8 + x4 * sh7)
                      - CCC * (x2 * sh7 + x3 * sh6);
            float yc4 = CCB * (x1 * sh5 - x3 * sh7) + CCA * (x2 * sh8 + x4 * sh6);
#pragma unroll
            for (int w = 0; w < 4; ++w) {
                float wa = wd[u * 4 + w];
                float wb = wd[20 + u * 4 + w];
                float wc = wd[40 + u * 4 + w];
                float we = wd[60 + u * 4 + w];
                od0[w] = fmaf(dot, wc, od0[w]);
                od1[w * 3 + 0] = fmaf(yb0, wb, od1[w * 3 + 0]);
                od1[w * 3 + 1] = fmaf(yb1, wb, od1[w * 3 + 1]);
                od1[w * 3 + 2] = fmaf(yb2, wb, od1[w * 3 + 2]);
                od2[w * 5 + 0] = fmaf(x0, wa, fmaf(yc0, we, od2[w * 5 + 0]));
                od2[w * 5 + 1] = fmaf(x1, wa, fmaf(yc1, we, od2[w * 5 + 1]));
                od2[w * 5 + 2] = fmaf(x2, wa, fmaf(yc2, we, od2[w * 5 + 2]));
                od2[w * 5 + 3] = fmaf(x3, wa, fmaf(yc3, we, od2[w * 5 + 3]));
                od2[w * 5 + 4] = fmaf(x4, wa, fmaf(yc4, we, od2[w * 5 + 4]));
            }
        }
#pragma unroll
        for (int q = 0; q < 9; ++q) rowv[18 + q] = ((const float4*)b)[q];
    }
}

// ============ phase 4: per-node gather-reduce ============
__global__ __launch_bounds__(128) void reduce_kernel(const float* __restrict__ summand,
                                                     const int* __restrict__ offs,
                                                     float* __restrict__ out, int N) {
    int n = blockIdx.x;
    int t = threadIdx.x;
    if (t >= 108) return;
    int b = offs[n], e2 = offs[n + 1];
    float a0 = 0.f, a1 = 0.f;
    int p = b;
    for (; p + 1 < e2; p += 2) {
        a0 += summand[(size_t)p * 108 + t];
        a1 += summand[(size_t)(p + 1) * 108 + t];
    }
    if (p < e2) a0 += summand[(size_t)p * 108 + t];
    out[(size_t)n * 108 + t] = a0 + a1;
}

// ============ fallback: round-1 atomic kernel (if ws too small) ============
__global__ __launch_bounds__(TPB) void eqconv_edge_kernel_atomic(
    const float* __restrict__ f_in,
    const int*   __restrict__ eidx,
    const float* __restrict__ pos,
    const float* __restrict__ W1s_g, const float* __restrict__ W2s_g,
    const float* __restrict__ W1p_g, const float* __restrict__ W2p_g,
    const float* __restrict__ W1d_g, const float* __restrict__ W2d_g,
    float* __restrict__ out,
    int E, float snorm)
{
    __shared__ __align__(16) float smem[11264];
    float* tW1s = smem;
    float* tW1p = smem + 768;
    float* tW1d = smem + 1536;
    float* sW2s = smem + 2304;
    float* sW2p = smem + 3072;
    float* sW2d = smem + 6144;

    const int tid = threadIdx.x;
    const float base = 0.05590169943749474f * snorm;

    for (int idx = tid; idx < 768; idx += TPB) {
        int j = idx / 12, i = idx - j * 12;
        tW1s[idx] = (i < 10) ? W1s_g[i * 64 + j] : 0.f;
        tW1p[idx] = (i < 10) ? W1p_g[i * 64 + j] : 0.f;
        tW1d[idx] = (i < 10) ? W1d_g[i * 64 + j] : 0.f;
    }
    for (int idx = tid; idx < 768; idx += TPB)
        sW2s[idx] = W2s_g[idx] * base;
    for (int idx = tid; idx < 3072; idx += TPB) {
        int m = idx % 48;
        float k = (m < 12) ? 0.40824829046386307f
                : (m < 24) ? 0.33333333333333333f
                : (m < 36) ? 1.29099444873580560f
                           : 0.70710678118654752f;
        sW2p[idx] = W2p_g[idx] * (base * k);
    }
    for (int idx = tid; idx < 5120; idx += TPB) {
        int m = idx % 80;
        float k = (m < 20) ? 0.31622776601683794f
                : (m < 40) ? 0.77459666924148340f
                : (m < 60) ? 0.2f
                           : 0.70710678118654752f;
        sW2d[idx] = W2d_g[idx] * (base * k);
    }
    __syncthreads();

    int e = blockIdx.x * TPB + tid;
    if (e >= E) return;

    const int row = eidx[e];
    const int col = eidx[E + e];

    float ex = pos[row * 3 + 0] - pos[col * 3 + 0];
    float ey = pos[row * 3 + 1] - pos[col * 3 + 1];
    float ez = pos[row * 3 + 2] - pos[col * 3 + 2];
    float r = sqrtf(ex * ex + ey * ey + ez * ez + 1e-12f);
    float rinv = 1.0f / r;
    float x = ex * rinv, y = ey * rinv, z = ez * rinv;

    float sh1 = 1.7320508075688772f * x;
    float sh2 = 1.7320508075688772f * y;
    float sh3 = 1.7320508075688772f * z;
    float sh4 = 3.8729833462074170f * x * z;
    float sh5 = 3.8729833462074170f * x * y;
    float sh6 = 1.1180339887498949f * (2.f * y * y - x * x - z * z);
    float sh7 = 3.8729833462074170f * y * z;
    float sh8 = 1.9364916731037085f * (z * z - x * x);

    float emb[12];
    {
        const float F = (float)(1.14136 * 7.38905609893065 * 3.1622776601683795);
        const float inv_step = 2.2f;
#pragma unroll
        for (int i = 0; i < 10; ++i) {
            float v = (float)(i + 1) * (5.0f / 11.0f);
            float d = (r - v) * inv_step;
            float d2 = d * d;
            emb[i] = (d2 < 1.0f) ? F * expf(-2.0f / (1.0f - d2)) : 0.f;
        }
        emb[10] = 0.f; emb[11] = 0.f;
    }

    const float* fr = f_in + (size_t)row * 162;
    float* o = out + (size_t)col * 108;

    {
        float ws[12];
        fc_eval<12>(tW1s, sW2s, emb, ws);
        float2 v0 = *(const float2*)(fr);
        float X = v0.x + v0.y;
#pragma unroll
        for (int w = 0; w < 4; ++w) {
            atomAddF(o + w, X * ws[w]);
            float t1 = X * ws[4 + w];
            atomAddF(o + 4 + w * 3 + 0, t1 * sh1);
            atomAddF(o + 4 + w * 3 + 1, t1 * sh2);
            atomAddF(o + 4 + w * 3 + 2, t1 * sh3);
            float t2 = X * ws[8 + w];
            atomAddF(o + 16 + w * 5 + 0, t2 * sh4);
            atomAddF(o + 16 + w * 5 + 1, t2 * sh5);
            atomAddF(o + 16 + w * 5 + 2, t2 * sh6);
            atomAddF(o + 16 + w * 5 + 3, t2 * sh7);
            atomAddF(o + 16 + w * 5 + 4, t2 * sh8);
        }
    }
    {
        float wp[48];
        fc_eval<48>(tW1p, sW2p, emb, wp);
        float op0[4] = {0.f,0.f,0.f,0.f};
        float op1[12], op2[20];
#pragma unroll
        for (int t = 0; t < 12; ++t) op1[t] = 0.f;
#pragma unroll
        for (int t = 0; t < 20; ++t) op2[t] = 0.f;
#pragma unroll
        for (int u = 0; u < 3; ++u) {
            float2 a0 = *(const float2*)(fr + ((1 + u) * 9 + 1) * 2);
            float2 a1 = *(const float2*)(fr + ((1 + u) * 9 + 2) * 2);
            float2 a2 = *(const float2*)(fr + ((1 + u) * 9 + 3) * 2);
            float x0 = a0.x + a0.y, x1 = a1.x + a1.y, x2 = a2.x + a2.y;
            float dot = x0 * sh1 + x1 * sh2 + x2 * sh3;
            float ya0 = R10 * (x0 * sh3 + x2 * sh1);
            float ya1 = R10 * (x0 * sh2 + x1 * sh1);
            float ya2 = R30 * (2.f * x1 * sh2 - x0 * sh1 - x2 * sh3);
            float ya3 = R10 * (x1 * sh3 + x2 * sh2);
            float ya4 = R10 * (x2 * sh3 - x0 * sh1);
            float yb0 = R10 * (x2 * sh4 + x1 * sh5 - x0 * sh8) - R30 * x0 * sh6;
            float yb1 = R10 * (x0 * sh5 + x2 * sh7) + R30x2 * x1 * sh6;
            float yb2 = R10 * (x0 * sh4 + x1 * sh7 + x2 * sh8) - R30 * x2 * sh6;
#pragma unroll
            for (int w = 0; w < 4; ++w) {
                float wa = wp[u * 4 + w];
                float wb = wp[12 + u * 4 + w];
                float wc = wp[24 + u * 4 + w];
                float wd2 = wp[36 + u * 4 + w];
                op0[w] = fmaf(dot, wb, op0[w]);
                op1[w * 3 + 0] = fmaf(x0, wa, fmaf(yb0, wd2, op1[w * 3 + 0]));
                op1[w * 3 + 1] = fmaf(x1, wa, fmaf(yb1, wd2, op1[w * 3 + 1]));
                op1[w * 3 + 2] = fmaf(x2, wa, fmaf(yb2, wd2, op1[w * 3 + 2]));
                op2[w * 5 + 0] = fmaf(ya0, wc, op2[w * 5 + 0]);
                op2[w * 5 + 1] = fmaf(ya1, wc, op2[w * 5 + 1]);
                op2[w * 5 + 2] = fmaf(ya2, wc, op2[w * 5 + 2]);
                op2[w * 5 + 3] = fmaf(ya3, wc, op2[w * 5 + 3]);
                op2[w * 5 + 4] = fmaf(ya4, wc, op2[w * 5 + 4]);
            }
        }
#pragma unroll
        for (int w = 0; w < 4; ++w) atomAddF(o + 36 + w, op0[w]);
#pragma unroll
        for (int t = 0; t < 12; ++t) atomAddF(o + 40 + t, op1[t]);
#pragma unroll
        for (int t = 0; t < 20; ++t) atomAddF(o + 52 + t, op2[t]);
    }
    {
        float wd[80];
        fc_eval<80>(tW1d, sW2d, emb, wd);
        float od0[4] = {0.f,0.f,0.f,0.f};
        float od1[12], od2[20];
#pragma unroll
        for (int t = 0; t < 12; ++t) od1[t] = 0.f;
#pragma unroll
        for (int t = 0; t < 20; ++t) od2[t] = 0.f;
#pragma unroll
        for (int u = 0; u < 5; ++u) {
            float2 b0 = *(const float2*)(fr + ((4 + u) * 9 + 4) * 2);
            float2 b1 = *(const float2*)(fr + ((4 + u) * 9 + 5) * 2);
            float2 b2 = *(const float2*)(fr + ((4 + u) * 9 + 6) * 2);
            float2 b3 = *(const float2*)(fr + ((4 + u) * 9 + 7) * 2);
            float2 b4 = *(const float2*)(fr + ((4 + u) * 9 + 8) * 2);
            float x0 = b0.x + b0.y, x1 = b1.x + b1.y, x2 = b2.x + b2.y;
            float x3 = b3.x + b3.y, x4 = b4.x + b4.y;
            float dot = x0 * sh4 + x1 * sh5 + x2 * sh6 + x3 * sh7 + x4 * sh8;
            float yb0 = R10 * (x0 * sh3 + x1 * sh2 - x4 * sh1) - R30 * x2 * sh1;
            float yb1 = R10 * (x1 * sh1 + x3 * sh3) + R30x2 * x2 * sh2;
            float yb2 = R10 * (x0 * sh1 + x3 * sh2 + x4 * sh3) - R30 * x2 * sh3;
            float yc0 = CCA * (x2 * sh4 + x0 * sh6) - CCB * (x1 * sh7 + x3 * sh5);
            float yc1 = CCB * (x1 * sh8 + x4 * sh5 - x0 * sh7 - x3 * sh4)
                      - CCC * (x1 * sh6 + x2 * sh5);
            float yc2 = CCA * (x0 * sh4 - x2 * sh6 + x4 * sh8)
                      - CCC * (x1 * sh5 + x3 * sh7);
            float yc3 = -CCB * (x0 * sh5 + x1 * sh4 + x3 * sh8 + x4 * sh7)
                      - CCC * (x2 * sh7 + x3 * sh6);
            float yc4 = CCB * (x1 * sh5 - x3 * sh7) + CCA * (x2 * sh8 + x4 * sh6);
#pragma unroll
            for (int w = 0; w < 4; ++w) {
                float wa = wd[u * 4 + w];
                float wb = wd[20 + u * 4 + w];
                float wc = wd[40 + u * 4 + w];
                float we = wd[60 + u * 4 + w];
                od0[w] = fmaf(dot, wc, od0[w]);
                od1[w * 3 + 0] = fmaf(yb0, wb, od1[w * 3 + 0]);
                od1[w * 3 + 1] = fmaf(yb1, wb, od1[w * 3 + 1]);
                od1[w * 3 + 2] = fmaf(yb2, wb, od1[w * 3 + 2]);
                od2[w * 5 + 0] = fmaf(x0, wa, fmaf(yc0, we, od2[w * 5 + 0]));
                od2[w * 5 + 1] = fmaf(x1, wa, fmaf(yc1, we, od2[w * 5 + 1]));
                od2[w * 5 + 2] = fmaf(x2, wa, fmaf(yc2, we, od2[w * 5 + 2]));
                od2[w * 5 + 3] = fmaf(x3, wa, fmaf(yc3, we, od2[w * 5 + 3]));
                od2[w * 5 + 4] = fmaf(x4, wa, fmaf(yc4, we, od2[w * 5 + 4]));
            }
        }
#pragma unroll
        for (int w = 0; w < 4; ++w) atomAddF(o + 72 + w, od0[w]);
#pragma unroll
        for (int t = 0; t < 12; ++t) atomAddF(o + 76 + t, od1[t]);
#pragma unroll
        for (int t = 0; t < 20; ++t) atomAddF(o + 88 + t, od2[t]);
    }
}

extern "C" void kernel_launch(void* const* d_in, const int* in_sizes, int n_in,
                              void* d_out, int out_size, void* d_ws, size_t ws_size,
                              hipStream_t stream) {
    const float* f_in = (const float*)d_in[0];
    const int*   eidx = (const int*)d_in[1];
    const float* pos  = (const float*)d_in[2];
    const float* W1s = (const float*)d_in[5];
    const float* W2s = (const float*)d_in[6];
    const float* W1p = (const float*)d_in[7];
    const float* W2p = (const float*)d_in[8];
    const float* W1d = (const float*)d_in[9];
    const float* W2d = (const float*)d_in[10];

    const int E = in_sizes[1] / 2;
    const int N = in_sizes[0] / 162;
    const float snorm = (float)(1.0 / sqrt((double)E / (double)N));

    const size_t headBytes = (size_t)(3 * N + 1) * sizeof(int);
    const size_t sumOff = ((headBytes + 255) / 256) * 256;
    const size_t need = sumOff + (size_t)E * 108 * sizeof(float);

    if (ws_size >= need) {
        int* cnt    = (int*)d_ws;
        int* offs   = cnt + N;
        int* cursor = offs + N + 1;
        float* summand = (float*)((char*)d_ws + sumOff);

        hipMemsetAsync(cnt, 0, (size_t)N * sizeof(int), stream);
        count_kernel<<<(E + 255) / 256, 256, 0, stream>>>(eidx + E, cnt, E);
        scan_kernel<<<1, 1024, 0, stream>>>(cnt, offs, cursor, N);
        eqconv_compute_kernel<<<(E + TPB - 1) / TPB, TPB, 0, stream>>>(
            f_in, eidx, pos, W1s, W2s, W1p, W2p, W1d, W2d,
            cursor, summand, E, snorm);
        reduce_kernel<<<N, 128, 0, stream>>>(summand, offs, (float*)d_out, N);
    } else {
        hipMemsetAsync(d_out, 0, (size_t)out_size * sizeof(float), stream);
        eqconv_edge_kernel_atomic<<<(E + TPB - 1) / TPB, TPB, 0, stream>>>(
            f_in, eidx, pos, W1s, W2s, W1p, W2p, W1d, W2d,
            (float*)d_out, E, snorm);
    }
}

// Round 3
// 705.479 us; speedup vs baseline: 6.6240x; 6.6159x over previous
//
#include <hip/hip_runtime.h>
#include <math.h>

#define TPB 256

// ---- analytic Wigner-3j constants (verified R1: absmax 0.0156) ----
#define R10   0.31622776601683794f  // 1/sqrt(10)
#define R30   0.18257418583505536f  // 1/sqrt(30)
#define R30x2 0.36514837167011072f  // 2/sqrt(30)
#define C222_SIGN (1.0f)            // verified R1
#define CCA (C222_SIGN * 0.23904572186687872f) // 2/sqrt(70)
#define CCB (C222_SIGN * 0.20701966780270623f) // sqrt(3/70)
#define CCC (C222_SIGN * 0.11952286093343936f) // 1/sqrt(70)

__device__ __forceinline__ void atomAddF(float* p, float v) {
    __hip_atomic_fetch_add(p, v, __ATOMIC_RELAXED, __HIP_MEMORY_SCOPE_AGENT);
}

template<int M>
__device__ __forceinline__ void fc_eval(const float* sW1T, const float* sW2,
                                        const float emb[12], float* acc)
{
#pragma unroll
    for (int m = 0; m < M; ++m) acc[m] = 0.f;
#pragma unroll 2
    for (int j = 0; j < 64; ++j) {
        const float4* w1r = (const float4*)(sW1T + j * 12);
        float4 A = w1r[0], B = w1r[1], C = w1r[2];
        float t = A.x*emb[0] + A.y*emb[1] + A.z*emb[2] + A.w*emb[3]
                + B.x*emb[4] + B.y*emb[5] + B.z*emb[6] + B.w*emb[7]
                + C.x*emb[8] + C.y*emb[9];
        t = fmaxf(t, 0.f);
        const float4* w2r = (const float4*)(sW2 + j * M);
#pragma unroll
        for (int q = 0; q < M / 4; ++q) {
            float4 V = w2r[q];
            acc[4*q+0] = fmaf(t, V.x, acc[4*q+0]);
            acc[4*q+1] = fmaf(t, V.y, acc[4*q+1]);
            acc[4*q+2] = fmaf(t, V.z, acc[4*q+2]);
            acc[4*q+3] = fmaf(t, V.w, acc[4*q+3]);
        }
    }
}

// ============ phase 1: histogram of col ============
__global__ __launch_bounds__(256) void count_kernel(const int* __restrict__ col,
                                                    int* __restrict__ cnt, int E) {
    int e = blockIdx.x * 256 + threadIdx.x;
    if (e < E) atomicAdd(&cnt[col[e]], 1);
}

// ============ phase 2: exclusive scan (1 block) ============
__global__ __launch_bounds__(1024) void scan_kernel(const int* __restrict__ cnt,
                                                    int* __restrict__ offs,
                                                    int* __restrict__ cursor, int N) {
    __shared__ int sdata[1024];
    __shared__ int stotal;
    const int tid = threadIdx.x;
    if (tid == 0) stotal = 0;
    __syncthreads();
    for (int base = 0; base < N; base += 4096) {
        int i0 = base + tid * 4;
        int v0 = (i0 + 0 < N) ? cnt[i0 + 0] : 0;
        int v1 = (i0 + 1 < N) ? cnt[i0 + 1] : 0;
        int v2 = (i0 + 2 < N) ? cnt[i0 + 2] : 0;
        int v3 = (i0 + 3 < N) ? cnt[i0 + 3] : 0;
        int s = v0 + v1 + v2 + v3;
        sdata[tid] = s;
        __syncthreads();
        for (int d = 1; d < 1024; d <<= 1) {
            int t = (tid >= d) ? sdata[tid - d] : 0;
            __syncthreads();
            sdata[tid] += t;
            __syncthreads();
        }
        int excl = sdata[tid] - s + stotal;
        if (i0 + 0 < N) { offs[i0 + 0] = excl; cursor[i0 + 0] = excl; }
        excl += v0;
        if (i0 + 1 < N) { offs[i0 + 1] = excl; cursor[i0 + 1] = excl; }
        excl += v1;
        if (i0 + 2 < N) { offs[i0 + 2] = excl; cursor[i0 + 2] = excl; }
        excl += v2;
        if (i0 + 3 < N) { offs[i0 + 3] = excl; cursor[i0 + 3] = excl; }
        __syncthreads();
        if (tid == 1023) stotal += sdata[1023];
        __syncthreads();
    }
    if (tid == 0) offs[N] = stotal;
}

// ============ phase 3: permute edge endpoints into sorted-by-col order ============
__global__ __launch_bounds__(256) void permute_kernel(const int* __restrict__ eidx,
                                                      int* __restrict__ cursor,
                                                      int* __restrict__ rowS,
                                                      int* __restrict__ colS, int E) {
    int e = blockIdx.x * 256 + threadIdx.x;
    if (e < E) {
        int c = eidx[E + e];
        int p = atomicAdd(&cursor[c], 1);
        rowS[p] = eidx[e];
        colS[p] = c;
    }
}

// ============ phase 4: fused per-edge compute + in-LDS segmented reduce ============
__global__ __launch_bounds__(TPB) void fused_kernel(
    const float* __restrict__ f_in,
    const float* __restrict__ pos,
    const int*   __restrict__ rowS,
    const int*   __restrict__ colS,
    const int*   __restrict__ offs,
    const float* __restrict__ W1s_g, const float* __restrict__ W2s_g,
    const float* __restrict__ W1p_g, const float* __restrict__ W2p_g,
    const float* __restrict__ W1d_g, const float* __restrict__ W2d_g,
    float* __restrict__ out,
    int E, float snorm)
{
    __shared__ __align__(16) float smem[2304 + 5120 + 256 * 19];
    float* tW1   = smem;            // 3 x (64x12), W1^T padded 10->12
    float* W2buf = smem + 2304;     // staged per path (<= 64x80)
    float* red   = smem + 7424;     // 256 x 19 (18 + 1 pad)
    __shared__ int sNode[256];
    __shared__ int sScan[256];
    __shared__ int segStart[257];

    const int tid = threadIdx.x;
    const int B = blockIdx.x * TPB;
    const int p = B + tid;
    const bool valid = p < E;
    const int validCount = min(TPB, E - B);
    const float base = 0.05590169943749474f * snorm; // sqrt2/(8*sqrt10) * snorm

    const int myNode = valid ? colS[p] : 0x7fffffff;
    sNode[tid] = myNode;

    // stage W1^T (all paths) and W2s before the first barrier
    for (int idx = tid; idx < 768; idx += TPB) {
        int j = idx / 12, i = idx - j * 12;
        tW1[idx]        = (i < 10) ? W1s_g[i * 64 + j] : 0.f;
        tW1[768 + idx]  = (i < 10) ? W1p_g[i * 64 + j] : 0.f;
        tW1[1536 + idx] = (i < 10) ? W1d_g[i * 64 + j] : 0.f;
        W2buf[idx] = W2s_g[idx] * base;                 // S path consts all == 1
    }
    __syncthreads();

    // segment heads + block-wide inclusive scan of head flags
    int head = (valid && (tid == 0 || sNode[tid] != sNode[tid - 1])) ? 1 : 0;
    sScan[tid] = head;
    __syncthreads();
#pragma unroll
    for (int d = 1; d < 256; d <<= 1) {
        int t = (tid >= d) ? sScan[tid - d] : 0;
        __syncthreads();
        sScan[tid] += t;
        __syncthreads();
    }
    const int nSeg = sScan[255];
    if (head) segStart[sScan[tid] - 1] = tid;
    if (tid == 0) segStart[nSeg] = validCount;
    __syncthreads();

    // segmented-reduce helper: reads red[t*19 + j] (j in [0,18)), writes out
    auto reduce_chunk = [&](int outBase) {
        for (int i = tid; i < nSeg * 18; i += TPB) {
            int seg = i / 18;
            int j = i - seg * 18;
            int s0 = segStart[seg], s1 = segStart[seg + 1];
            float acc = 0.f;
            for (int t = s0; t < s1; ++t) acc += red[t * 19 + j];
            int n = sNode[s0];
            bool partial = (seg == 0 && offs[n] < B) ||
                           (seg == nSeg - 1 && offs[n + 1] > B + TPB);
            float* dst = out + (size_t)n * 108 + outBase + j;
            if (partial) atomAddF(dst, acc);
            else         *dst = acc;
        }
    };

    // ---- per-edge geometry (safe defaults for invalid lanes) ----
    const int row  = valid ? rowS[p] : 0;
    const int colN = valid ? myNode : 0;
    const float fm = valid ? 1.f : 0.f;

    float ex = pos[row * 3 + 0] - pos[colN * 3 + 0];
    float ey = pos[row * 3 + 1] - pos[colN * 3 + 1];
    float ez = pos[row * 3 + 2] - pos[colN * 3 + 2];
    float r = sqrtf(ex * ex + ey * ey + ez * ez + 1e-12f);
    float rinv = 1.0f / r;
    float x = ex * rinv, y = ey * rinv, z = ez * rinv;

    float sh1 = 1.7320508075688772f * x;
    float sh2 = 1.7320508075688772f * y;
    float sh3 = 1.7320508075688772f * z;
    float sh4 = 3.8729833462074170f * x * z;
    float sh5 = 3.8729833462074170f * x * y;
    float sh6 = 1.1180339887498949f * (2.f * y * y - x * x - z * z);
    float sh7 = 3.8729833462074170f * y * z;
    float sh8 = 1.9364916731037085f * (z * z - x * x);

    float emb[12];
    {
        const float F = (float)(1.14136 * 7.38905609893065 * 3.1622776601683795);
        const float inv_step = 2.2f;
#pragma unroll
        for (int i = 0; i < 10; ++i) {
            float v = (float)(i + 1) * (5.0f / 11.0f);
            float d = (r - v) * inv_step;
            float d2 = d * d;
            emb[i] = (d2 < 1.0f) ? F * expf(-2.0f / (1.0f - d2)) : 0.f;
        }
        emb[10] = 0.f; emb[11] = 0.f;
    }

    const float* fr = f_in + (size_t)row * 162;
    float b[36];

    // ================= S path (out base 0) =================
    {
        float ws[12];
        fc_eval<12>(tW1, W2buf, emb, ws);
        float2 v0 = *(const float2*)(fr);
        float X = (v0.x + v0.y) * fm;
#pragma unroll
        for (int w = 0; w < 4; ++w) {
            b[w] = X * ws[w];
            float t1 = X * ws[4 + w];
            b[4 + w * 3 + 0] = t1 * sh1;
            b[4 + w * 3 + 1] = t1 * sh2;
            b[4 + w * 3 + 2] = t1 * sh3;
            float t2 = X * ws[8 + w];
            b[16 + w * 5 + 0] = t2 * sh4;
            b[16 + w * 5 + 1] = t2 * sh5;
            b[16 + w * 5 + 2] = t2 * sh6;
            b[16 + w * 5 + 3] = t2 * sh7;
            b[16 + w * 5 + 4] = t2 * sh8;
        }
    }
#pragma unroll
    for (int j = 0; j < 18; ++j) red[tid * 19 + j] = b[j];
    __syncthreads();
    reduce_chunk(0);
    __syncthreads();
#pragma unroll
    for (int j = 0; j < 18; ++j) red[tid * 19 + j] = b[18 + j];
    __syncthreads();
    reduce_chunk(18);
    // stage W2p (compute-S finished for all threads: safe to overwrite W2buf)
    for (int idx = tid; idx < 3072; idx += TPB) {
        int m = idx % 48;
        float k = (m < 12) ? 0.40824829046386307f
                : (m < 24) ? 0.33333333333333333f
                : (m < 36) ? 1.29099444873580560f
                           : 0.70710678118654752f;
        W2buf[idx] = W2p_g[idx] * (base * k);
    }
    __syncthreads();

    // ================= P path (out base 36) =================
    {
        float wp[48];
        fc_eval<48>(tW1 + 768, W2buf, emb, wp);
        float* op0 = b;       // 4
        float* op1 = b + 4;   // 12
        float* op2 = b + 16;  // 20
#pragma unroll
        for (int t = 0; t < 36; ++t) b[t] = 0.f;
#pragma unroll
        for (int u = 0; u < 3; ++u) {
            float2 a0 = *(const float2*)(fr + ((1 + u) * 9 + 1) * 2);
            float2 a1 = *(const float2*)(fr + ((1 + u) * 9 + 2) * 2);
            float2 a2 = *(const float2*)(fr + ((1 + u) * 9 + 3) * 2);
            float x0 = (a0.x + a0.y) * fm, x1 = (a1.x + a1.y) * fm, x2 = (a2.x + a2.y) * fm;
            float dot = x0 * sh1 + x1 * sh2 + x2 * sh3;
            float ya0 = R10 * (x0 * sh3 + x2 * sh1);
            float ya1 = R10 * (x0 * sh2 + x1 * sh1);
            float ya2 = R30 * (2.f * x1 * sh2 - x0 * sh1 - x2 * sh3);
            float ya3 = R10 * (x1 * sh3 + x2 * sh2);
            float ya4 = R10 * (x2 * sh3 - x0 * sh1);
            float yb0 = R10 * (x2 * sh4 + x1 * sh5 - x0 * sh8) - R30 * x0 * sh6;
            float yb1 = R10 * (x0 * sh5 + x2 * sh7) + R30x2 * x1 * sh6;
            float yb2 = R10 * (x0 * sh4 + x1 * sh7 + x2 * sh8) - R30 * x2 * sh6;
#pragma unroll
            for (int w = 0; w < 4; ++w) {
                float wa = wp[u * 4 + w];
                float wb = wp[12 + u * 4 + w];
                float wc = wp[24 + u * 4 + w];
                float wd2 = wp[36 + u * 4 + w];
                op0[w] = fmaf(dot, wb, op0[w]);
                op1[w * 3 + 0] = fmaf(x0, wa, fmaf(yb0, wd2, op1[w * 3 + 0]));
                op1[w * 3 + 1] = fmaf(x1, wa, fmaf(yb1, wd2, op1[w * 3 + 1]));
                op1[w * 3 + 2] = fmaf(x2, wa, fmaf(yb2, wd2, op1[w * 3 + 2]));
                op2[w * 5 + 0] = fmaf(ya0, wc, op2[w * 5 + 0]);
                op2[w * 5 + 1] = fmaf(ya1, wc, op2[w * 5 + 1]);
                op2[w * 5 + 2] = fmaf(ya2, wc, op2[w * 5 + 2]);
                op2[w * 5 + 3] = fmaf(ya3, wc, op2[w * 5 + 3]);
                op2[w * 5 + 4] = fmaf(ya4, wc, op2[w * 5 + 4]);
            }
        }
    }
#pragma unroll
    for (int j = 0; j < 18; ++j) red[tid * 19 + j] = b[j];
    __syncthreads();
    reduce_chunk(36);
    __syncthreads();
#pragma unroll
    for (int j = 0; j < 18; ++j) red[tid * 19 + j] = b[18 + j];
    __syncthreads();
    reduce_chunk(54);
    // stage W2d
    for (int idx = tid; idx < 5120; idx += TPB) {
        int m = idx % 80;
        float k = (m < 20) ? 0.31622776601683794f
                : (m < 40) ? 0.77459666924148340f
                : (m < 60) ? 0.2f
                           : 0.70710678118654752f;
        W2buf[idx] = W2d_g[idx] * (base * k);
    }
    __syncthreads();

    // ================= D path (out base 72) =================
    {
        float wd[80];
        fc_eval<80>(tW1 + 1536, W2buf, emb, wd);
        float* od0 = b;       // 4
        float* od1 = b + 4;   // 12
        float* od2 = b + 16;  // 20
#pragma unroll
        for (int t = 0; t < 36; ++t) b[t] = 0.f;
#pragma unroll
        for (int u = 0; u < 5; ++u) {
            float2 b0 = *(const float2*)(fr + ((4 + u) * 9 + 4) * 2);
            float2 b1 = *(const float2*)(fr + ((4 + u) * 9 + 5) * 2);
            float2 b2 = *(const float2*)(fr + ((4 + u) * 9 + 6) * 2);
            float2 b3 = *(const float2*)(fr + ((4 + u) * 9 + 7) * 2);
            float2 b4 = *(const float2*)(fr + ((4 + u) * 9 + 8) * 2);
            float x0 = (b0.x + b0.y) * fm, x1 = (b1.x + b1.y) * fm, x2 = (b2.x + b2.y) * fm;
            float x3 = (b3.x + b3.y) * fm, x4 = (b4.x + b4.y) * fm;
            float dot = x0 * sh4 + x1 * sh5 + x2 * sh6 + x3 * sh7 + x4 * sh8;
            float yb0 = R10 * (x0 * sh3 + x1 * sh2 - x4 * sh1) - R30 * x2 * sh1;
            float yb1 = R10 * (x1 * sh1 + x3 * sh3) + R30x2 * x2 * sh2;
            float yb2 = R10 * (x0 * sh1 + x3 * sh2 + x4 * sh3) - R30 * x2 * sh3;
            float yc0 = CCA * (x2 * sh4 + x0 * sh6) - CCB * (x1 * sh7 + x3 * sh5);
            float yc1 = CCB * (x1 * sh8 + x4 * sh5 - x0 * sh7 - x3 * sh4)
                      - CCC * (x1 * sh6 + x2 * sh5);
            float yc2 = CCA * (x0 * sh4 - x2 * sh6 + x4 * sh8)
                      - CCC * (x1 * sh5 + x3 * sh7);
            float yc3 = -CCB * (x0 * sh5 + x1 * sh4 + x3 * sh8 + x4 * sh7)
                      - CCC * (x2 * sh7 + x3 * sh6);
            float yc4 = CCB * (x1 * sh5 - x3 * sh7) + CCA * (x2 * sh8 + x4 * sh6);
#pragma unroll
            for (int w = 0; w < 4; ++w) {
                float wa = wd[u * 4 + w];
                float wb = wd[20 + u * 4 + w];
                float wc = wd[40 + u * 4 + w];
                float we = wd[60 + u * 4 + w];
                od0[w] = fmaf(dot, wc, od0[w]);
                od1[w * 3 + 0] = fmaf(yb0, wb, od1[w * 3 + 0]);
                od1[w * 3 + 1] = fmaf(yb1, wb, od1[w * 3 + 1]);
                od1[w * 3 + 2] = fmaf(yb2, wb, od1[w * 3 + 2]);
                od2[w * 5 + 0] = fmaf(x0, wa, fmaf(yc0, we, od2[w * 5 + 0]));
                od2[w * 5 + 1] = fmaf(x1, wa, fmaf(yc1, we, od2[w * 5 + 1]));
                od2[w * 5 + 2] = fmaf(x2, wa, fmaf(yc2, we, od2[w * 5 + 2]));
                od2[w * 5 + 3] = fmaf(x3, wa, fmaf(yc3, we, od2[w * 5 + 3]));
                od2[w * 5 + 4] = fmaf(x4, wa, fmaf(yc4, we, od2[w * 5 + 4]));
            }
        }
    }
#pragma unroll
    for (int j = 0; j < 18; ++j) red[tid * 19 + j] = b[j];
    __syncthreads();
    reduce_chunk(72);
    __syncthreads();
#pragma unroll
    for (int j = 0; j < 18; ++j) red[tid * 19 + j] = b[18 + j];
    __syncthreads();
    reduce_chunk(90);
}

// ============ fallback: round-1 atomic kernel (if ws too small) ============
__global__ __launch_bounds__(TPB) void eqconv_edge_kernel_atomic(
    const float* __restrict__ f_in,
    const int*   __restrict__ eidx,
    const float* __restrict__ pos,
    const float* __restrict__ W1s_g, const float* __restrict__ W2s_g,
    const float* __restrict__ W1p_g, const float* __restrict__ W2p_g,
    const float* __restrict__ W1d_g, const float* __restrict__ W2d_g,
    float* __restrict__ out,
    int E, float snorm)
{
    __shared__ __align__(16) float smem[11264];
    float* tW1s = smem;
    float* tW1p = smem + 768;
    float* tW1d = smem + 1536;
    float* sW2s = smem + 2304;
    float* sW2p = smem + 3072;
    float* sW2d = smem + 6144;

    const int tid = threadIdx.x;
    const float base = 0.05590169943749474f * snorm;

    for (int idx = tid; idx < 768; idx += TPB) {
        int j = idx / 12, i = idx - j * 12;
        tW1s[idx] = (i < 10) ? W1s_g[i * 64 + j] : 0.f;
        tW1p[idx] = (i < 10) ? W1p_g[i * 64 + j] : 0.f;
        tW1d[idx] = (i < 10) ? W1d_g[i * 64 + j] : 0.f;
    }
    for (int idx = tid; idx < 768; idx += TPB)
        sW2s[idx] = W2s_g[idx] * base;
    for (int idx = tid; idx < 3072; idx += TPB) {
        int m = idx % 48;
        float k = (m < 12) ? 0.40824829046386307f
                : (m < 24) ? 0.33333333333333333f
                : (m < 36) ? 1.29099444873580560f
                           : 0.70710678118654752f;
        sW2p[idx] = W2p_g[idx] * (base * k);
    }
    for (int idx = tid; idx < 5120; idx += TPB) {
        int m = idx % 80;
        float k = (m < 20) ? 0.31622776601683794f
                : (m < 40) ? 0.77459666924148340f
                : (m < 60) ? 0.2f
                           : 0.70710678118654752f;
        sW2d[idx] = W2d_g[idx] * (base * k);
    }
    __syncthreads();

    int e = blockIdx.x * TPB + tid;
    if (e >= E) return;

    const int row = eidx[e];
    const int col = eidx[E + e];

    float ex = pos[row * 3 + 0] - pos[col * 3 + 0];
    float ey = pos[row * 3 + 1] - pos[col * 3 + 1];
    float ez = pos[row * 3 + 2] - pos[col * 3 + 2];
    float r = sqrtf(ex * ex + ey * ey + ez * ez + 1e-12f);
    float rinv = 1.0f / r;
    float x = ex * rinv, y = ey * rinv, z = ez * rinv;

    float sh1 = 1.7320508075688772f * x;
    float sh2 = 1.7320508075688772f * y;
    float sh3 = 1.7320508075688772f * z;
    float sh4 = 3.8729833462074170f * x * z;
    float sh5 = 3.8729833462074170f * x * y;
    float sh6 = 1.1180339887498949f * (2.f * y * y - x * x - z * z);
    float sh7 = 3.8729833462074170f * y * z;
    float sh8 = 1.9364916731037085f * (z * z - x * x);

    float emb[12];
    {
        const float F = (float)(1.14136 * 7.38905609893065 * 3.1622776601683795);
        const float inv_step = 2.2f;
#pragma unroll
        for (int i = 0; i < 10; ++i) {
            float v = (float)(i + 1) * (5.0f / 11.0f);
            float d = (r - v) * inv_step;
            float d2 = d * d;
            emb[i] = (d2 < 1.0f) ? F * expf(-2.0f / (1.0f - d2)) : 0.f;
        }
        emb[10] = 0.f; emb[11] = 0.f;
    }

    const float* fr = f_in + (size_t)row * 162;
    float* o = out + (size_t)col * 108;

    {
        float ws[12];
        fc_eval<12>(tW1s, sW2s, emb, ws);
        float2 v0 = *(const float2*)(fr);
        float X = v0.x + v0.y;
#pragma unroll
        for (int w = 0; w < 4; ++w) {
            atomAddF(o + w, X * ws[w]);
            float t1 = X * ws[4 + w];
            atomAddF(o + 4 + w * 3 + 0, t1 * sh1);
            atomAddF(o + 4 + w * 3 + 1, t1 * sh2);
            atomAddF(o + 4 + w * 3 + 2, t1 * sh3);
            float t2 = X * ws[8 + w];
            atomAddF(o + 16 + w * 5 + 0, t2 * sh4);
            atomAddF(o + 16 + w * 5 + 1, t2 * sh5);
            atomAddF(o + 16 + w * 5 + 2, t2 * sh6);
            atomAddF(o + 16 + w * 5 + 3, t2 * sh7);
            atomAddF(o + 16 + w * 5 + 4, t2 * sh8);
        }
    }
    {
        float wp[48];
        fc_eval<48>(tW1p, sW2p, emb, wp);
        float op0[4] = {0.f,0.f,0.f,0.f};
        float op1[12], op2[20];
#pragma unroll
        for (int t = 0; t < 12; ++t) op1[t] = 0.f;
#pragma unroll
        for (int t = 0; t < 20; ++t) op2[t] = 0.f;
#pragma unroll
        for (int u = 0; u < 3; ++u) {
            float2 a0 = *(const float2*)(fr + ((1 + u) * 9 + 1) * 2);
            float2 a1 = *(const float2*)(fr + ((1 + u) * 9 + 2) * 2);
            float2 a2 = *(const float2*)(fr + ((1 + u) * 9 + 3) * 2);
            float x0 = a0.x + a0.y, x1 = a1.x + a1.y, x2 = a2.x + a2.y;
            float dot = x0 * sh1 + x1 * sh2 + x2 * sh3;
            float ya0 = R10 * (x0 * sh3 + x2 * sh1);
            float ya1 = R10 * (x0 * sh2 + x1 * sh1);
            float ya2 = R30 * (2.f * x1 * sh2 - x0 * sh1 - x2 * sh3);
            float ya3 = R10 * (x1 * sh3 + x2 * sh2);
            float ya4 = R10 * (x2 * sh3 - x0 * sh1);
            float yb0 = R10 * (x2 * sh4 + x1 * sh5 - x0 * sh8) - R30 * x0 * sh6;
            float yb1 = R10 * (x0 * sh5 + x2 * sh7) + R30x2 * x1 * sh6;
            float yb2 = R10 * (x0 * sh4 + x1 * sh7 + x2 * sh8) - R30 * x2 * sh6;
#pragma unroll
            for (int w = 0; w < 4; ++w) {
                float wa = wp[u * 4 + w];
                float wb = wp[12 + u * 4 + w];
                float wc = wp[24 + u * 4 + w];
                float wd2 = wp[36 + u * 4 + w];
                op0[w] = fmaf(dot, wb, op0[w]);
                op1[w * 3 + 0] = fmaf(x0, wa, fmaf(yb0, wd2, op1[w * 3 + 0]));
                op1[w * 3 + 1] = fmaf(x1, wa, fmaf(yb1, wd2, op1[w * 3 + 1]));
                op1[w * 3 + 2] = fmaf(x2, wa, fmaf(yb2, wd2, op1[w * 3 + 2]));
                op2[w * 5 + 0] = fmaf(ya0, wc, op2[w * 5 + 0]);
                op2[w * 5 + 1] = fmaf(ya1, wc, op2[w * 5 + 1]);
                op2[w * 5 + 2] = fmaf(ya2, wc, op2[w * 5 + 2]);
                op2[w * 5 + 3] = fmaf(ya3, wc, op2[w * 5 + 3]);
                op2[w * 5 + 4] = fmaf(ya4, wc, op2[w * 5 + 4]);
            }
        }
#pragma unroll
        for (int w = 0; w < 4; ++w) atomAddF(o + 36 + w, op0[w]);
#pragma unroll
        for (int t = 0; t < 12; ++t) atomAddF(o + 40 + t, op1[t]);
#pragma unroll
        for (int t = 0; t < 20; ++t) atomAddF(o + 52 + t, op2[t]);
    }
    {
        float wd[80];
        fc_eval<80>(tW1d, sW2d, emb, wd);
        float od0[4] = {0.f,0.f,0.f,0.f};
        float od1[12], od2[20];
#pragma unroll
        for (int t = 0; t < 12; ++t) od1[t] = 0.f;
#pragma unroll
        for (int t = 0; t < 20; ++t) od2[t] = 0.f;
#pragma unroll
        for (int u = 0; u < 5; ++u) {
            float2 b0 = *(const float2*)(fr + ((4 + u) * 9 + 4) * 2);
            float2 b1 = *(const float2*)(fr + ((4 + u) * 9 + 5) * 2);
            float2 b2 = *(const float2*)(fr + ((4 + u) * 9 + 6) * 2);
            float2 b3 = *(const float2*)(fr + ((4 + u) * 9 + 7) * 2);
            float2 b4 = *(const float2*)(fr + ((4 + u) * 9 + 8) * 2);
            float x0 = b0.x + b0.y, x1 = b1.x + b1.y, x2 = b2.x + b2.y;
            float x3 = b3.x + b3.y, x4 = b4.x + b4.y;
            float dot = x0 * sh4 + x1 * sh5 + x2 * sh6 + x3 * sh7 + x4 * sh8;
            float yb0 = R10 * (x0 * sh3 + x1 * sh2 - x4 * sh1) - R30 * x2 * sh1;
            float yb1 = R10 * (x1 * sh1 + x3 * sh3) + R30x2 * x2 * sh2;
            float yb2 = R10 * (x0 * sh1 + x3 * sh2 + x4 * sh3) - R30 * x2 * sh3;
            float yc0 = CCA * (x2 * sh4 + x0 * sh6) - CCB * (x1 * sh7 + x3 * sh5);
            float yc1 = CCB * (x1 * sh8 + x4 * sh5 - x0 * sh7 - x3 * sh4)
                      - CCC * (x1 * sh6 + x2 * sh5);
            float yc2 = CCA * (x0 * sh4 - x2 * sh6 + x4 * sh8)
                      - CCC * (x1 * sh5 + x3 * sh7);
            float yc3 = -CCB * (x0 * sh5 + x1 * sh4 + x3 * sh8 + x4 * sh7)
                      - CCC * (x2 * sh7 + x3 * sh6);
            float yc4 = CCB * (x1 * sh5 - x3 * sh7) + CCA * (x2 * sh8 + x4 * sh6);
#pragma unroll
            for (int w = 0; w < 4; ++w) {
                float wa = wd[u * 4 + w];
                float wb = wd[20 + u * 4 + w];
                float wc = wd[40 + u * 4 + w];
                float we = wd[60 + u * 4 + w];
                od0[w] = fmaf(dot, wc, od0[w]);
                od1[w * 3 + 0] = fmaf(yb0, wb, od1[w * 3 + 0]);
                od1[w * 3 + 1] = fmaf(yb1, wb, od1[w * 3 + 1]);
                od1[w * 3 + 2] = fmaf(yb2, wb, od1[w * 3 + 2]);
                od2[w * 5 + 0] = fmaf(x0, wa, fmaf(yc0, we, od2[w * 5 + 0]));
                od2[w * 5 + 1] = fmaf(x1, wa, fmaf(yc1, we, od2[w * 5 + 1]));
                od2[w * 5 + 2] = fmaf(x2, wa, fmaf(yc2, we, od2[w * 5 + 2]));
                od2[w * 5 + 3] = fmaf(x3, wa, fmaf(yc3, we, od2[w * 5 + 3]));
                od2[w * 5 + 4] = fmaf(x4, wa, fmaf(yc4, we, od2[w * 5 + 4]));
            }
        }
#pragma unroll
        for (int w = 0; w < 4; ++w) atomAddF(o + 72 + w, od0[w]);
#pragma unroll
        for (int t = 0; t < 12; ++t) atomAddF(o + 76 + t, od1[t]);
#pragma unroll
        for (int t = 0; t < 20; ++t) atomAddF(o + 88 + t, od2[t]);
    }
}

extern "C" void kernel_launch(void* const* d_in, const int* in_sizes, int n_in,
                              void* d_out, int out_size, void* d_ws, size_t ws_size,
                              hipStream_t stream) {
    const float* f_in = (const float*)d_in[0];
    const int*   eidx = (const int*)d_in[1];
    const float* pos  = (const float*)d_in[2];
    const float* W1s = (const float*)d_in[5];
    const float* W2s = (const float*)d_in[6];
    const float* W1p = (const float*)d_in[7];
    const float* W2p = (const float*)d_in[8];
    const float* W1d = (const float*)d_in[9];
    const float* W2d = (const float*)d_in[10];

    const int E = in_sizes[1] / 2;
    const int N = in_sizes[0] / 162;
    const float snorm = (float)(1.0 / sqrt((double)E / (double)N));
    const int eBlocks = (E + TPB - 1) / TPB;

    // ws layout: cnt[N] | offs[N+1] | cursor[N] | rowS[E] | colS[E]
    const size_t needInts = (size_t)(3 * N + 1) + 2 * (size_t)E;
    const size_t need = needInts * sizeof(int);

    if (ws_size >= need) {
        int* cnt    = (int*)d_ws;
        int* offs   = cnt + N;
        int* cursor = offs + N + 1;
        int* rowS   = cursor + N;
        int* colS   = rowS + E;

        hipMemsetAsync(cnt, 0, (size_t)N * sizeof(int), stream);
        hipMemsetAsync(d_out, 0, (size_t)out_size * sizeof(float), stream);
        count_kernel<<<eBlocks, 256, 0, stream>>>(eidx + E, cnt, E);
        scan_kernel<<<1, 1024, 0, stream>>>(cnt, offs, cursor, N);
        permute_kernel<<<eBlocks, 256, 0, stream>>>(eidx, cursor, rowS, colS, E);
        fused_kernel<<<eBlocks, TPB, 0, stream>>>(
            f_in, pos, rowS, colS, offs,
            W1s, W2s, W1p, W2p, W1d, W2d,
            (float*)d_out, E, snorm);
    } else {
        hipMemsetAsync(d_out, 0, (size_t)out_size * sizeof(float), stream);
        eqconv_edge_kernel_atomic<<<eBlocks, TPB, 0, stream>>>(
            f_in, eidx, pos, W1s, W2s, W1p, W2p, W1d, W2d,
            (float*)d_out, E, snorm);
    }
}